// Round 1
// baseline (347.972 us; speedup 1.0000x reference)
//
#include <hip/hip_runtime.h>
#include <math.h>

#define EPS 1e-6f
#define CH_L 64      // chunk length for EMA linear-recurrence decomposition
#define TG 16        // tokens per block in rms kernel

// ---------------------------------------------------------------------------
// Kernel 1: decay = sigmoid(logit), coef = 1-decay, and window length K such
// that max(decay)^K < 1e-12 (clamped to S). Computed on-device so the
// truncation is robust to any input values.
// ---------------------------------------------------------------------------
__global__ void k_prep(const float* __restrict__ logit, float* __restrict__ decay,
                       float* __restrict__ coef, int* __restrict__ Kp, int D, int S) {
    int tid = threadIdx.x;
    float local = 0.f;
    for (int d = tid; d < D; d += blockDim.x) {
        float dec = 1.f / (1.f + expf(-logit[d]));
        decay[d] = dec;
        coef[d]  = 1.f - dec;
        local = fmaxf(local, dec);
    }
    for (int off = 32; off; off >>= 1) local = fmaxf(local, __shfl_down(local, off));
    __shared__ float red[4];
    int wv = tid >> 6, ln = tid & 63;
    if (ln == 0) red[wv] = local;
    __syncthreads();
    if (tid == 0) {
        float maxd = fmaxf(fmaxf(red[0], red[1]), fmaxf(red[2], red[3]));
        float Kf;
        if (maxd <= 0.f) {
            Kf = 1.f;
        } else {
            float lg = logf(maxd);
            if (lg >= 0.f) Kf = (float)S;            // decay rounds to 1.0
            else           Kf = logf(1e-12f) / lg;   // positive
        }
        int K = (Kf >= (float)S) ? S : ((int)Kf + 1);
        *Kp = K;
    }
}

// ---------------------------------------------------------------------------
// Kernel 2: inv_rms[b,t] = rsqrt(mean_d(x^2)+eps) for tokens inside the
// window. One block handles TG=16 tokens; blocks outside window early-exit.
// blockDim.x must be D/4 (=256).
// ---------------------------------------------------------------------------
__global__ void k_rms(const float4* __restrict__ x4, const int* __restrict__ Kp,
                      float* __restrict__ inv_rms, int B, int S, int D, int nchunk) {
    int tg = blockIdx.x, b = blockIdx.y;
    int K = *Kp;
    int cmax = K / CH_L; if (cmax > nchunk - 1) cmax = nchunk - 1;
    int maxdist = (cmax + 1) * CH_L;         // tokens with dist < maxdist needed
    int t0 = tg * TG;
    if (S - (t0 + TG) >= maxdist) return;    // min distance in group >= maxdist
    int tid = threadIdx.x;
    int d4 = D >> 2;
    float s[TG];
#pragma unroll
    for (int i = 0; i < TG; i++) {
        float4 v = x4[((size_t)(b * S + t0 + i)) * d4 + tid];
        s[i] = v.x * v.x + v.y * v.y + v.z * v.z + v.w * v.w;
    }
#pragma unroll
    for (int i = 0; i < TG; i++)
        for (int off = 32; off; off >>= 1) s[i] += __shfl_down(s[i], off);
    __shared__ float red[4][TG];
    int wv = tid >> 6, ln = tid & 63;
    if (ln == 0) {
#pragma unroll
        for (int i = 0; i < TG; i++) red[wv][i] = s[i];
    }
    __syncthreads();
    if (tid < TG) {
        float tot = red[0][tid] + red[1][tid] + red[2][tid] + red[3][tid];
        inv_rms[(size_t)b * S + t0 + tid] = rsqrtf(tot / (float)D + EPS);
    }
}

// ---------------------------------------------------------------------------
// Kernel 3: per-chunk EMA partials. Chunk c covers tokens [S-(c+1)L, S-cL).
// partial_c[d] = sum_t xnorm[t,d]*(1-dec)*dec^(chunk_end-1-t), so
// final = sum_c partial_c[d] * dec^(c*L). Blocks with c*L > K early-exit.
// blockDim.x = D/4 (=256), one float4 (4 d's) per thread.
// ---------------------------------------------------------------------------
__global__ void k_ema(const float4* __restrict__ x4, const float* __restrict__ inv_rms,
                      const float4* __restrict__ decay4, const float4* __restrict__ coef4,
                      const float4* __restrict__ w14, const int* __restrict__ Kp,
                      float4* __restrict__ partial4, int B, int S, int D, int nchunk) {
    int c = blockIdx.x, b = blockIdx.y;
    int K = *Kp;
    if (c * CH_L > K) return;
    int tid = threadIdx.x;
    int d4 = D >> 2;
    float4 dec = decay4[tid], cf = coef4[tid], w1 = w14[tid];
    float cx = cf.x * w1.x, cy = cf.y * w1.y, cz = cf.z * w1.z, cw = cf.w * w1.w;
    float4 acc = make_float4(0.f, 0.f, 0.f, 0.f);
    int t0 = S - (c + 1) * CH_L;
    const float4* xb = x4 + ((size_t)b * S + t0) * d4 + tid;
    const float* irp = inv_rms + (size_t)b * S + t0;
#pragma unroll 4
    for (int i = 0; i < CH_L; i++) {
        float ir = irp[i];
        float4 xv = xb[(size_t)i * d4];
        acc.x = acc.x * dec.x + xv.x * ir * cx;
        acc.y = acc.y * dec.y + xv.y * ir * cy;
        acc.z = acc.z * dec.z + xv.z * ir * cz;
        acc.w = acc.w * dec.w + xv.w * ir * cw;
    }
    partial4[((size_t)b * nchunk + c) * d4 + tid] = acc;
}

// ---------------------------------------------------------------------------
// Kernel 4: combine partials -> final state, residual add with x[:,S-1,:],
// rmsnorm2, write pool[b,d]. One block per b.
// ---------------------------------------------------------------------------
__global__ void k_pool(const float4* __restrict__ x4, const float4* __restrict__ partial4,
                       const float4* __restrict__ decay4, const float4* __restrict__ w24,
                       const int* __restrict__ Kp, float4* __restrict__ pool4,
                       int B, int S, int D, int nchunk) {
    int b = blockIdx.x;
    int tid = threadIdx.x;
    int K = *Kp;
    int cmax = K / CH_L; if (cmax > nchunk - 1) cmax = nchunk - 1;
    int d4 = D >> 2;
    float4 dec = decay4[tid];
    float4 st = make_float4(0.f, 0.f, 0.f, 0.f);
    for (int c = 0; c <= cmax; c++) {
        float4 p = partial4[((size_t)b * nchunk + c) * d4 + tid];
        float wx, wy, wz, ww;
        if (c == 0) { wx = wy = wz = ww = 1.f; }
        else {
            float e = (float)(c * CH_L);
            wx = powf(dec.x, e); wy = powf(dec.y, e);
            wz = powf(dec.z, e); ww = powf(dec.w, e);
        }
        st.x += p.x * wx; st.y += p.y * wy; st.z += p.z * wz; st.w += p.w * ww;
    }
    float4 xl = x4[((size_t)b * S + (S - 1)) * d4 + tid];
    float4 y = make_float4(xl.x + st.x, xl.y + st.y, xl.z + st.z, xl.w + st.w);
    float ss = y.x * y.x + y.y * y.y + y.z * y.z + y.w * y.w;
    for (int off = 32; off; off >>= 1) ss += __shfl_down(ss, off);
    __shared__ float red[4];
    __shared__ float tot;
    int wv = tid >> 6, ln = tid & 63;
    if (ln == 0) red[wv] = ss;
    __syncthreads();
    if (tid == 0) tot = red[0] + red[1] + red[2] + red[3];
    __syncthreads();
    float ir = rsqrtf(tot / (float)D + EPS);
    float4 w2 = w24[tid];
    float4 pl = make_float4(y.x * ir * w2.x, y.y * ir * w2.y,
                            y.z * ir * w2.z, y.w * ir * w2.w);
    pool4[(size_t)b * d4 + tid] = pl;
}

// ---------------------------------------------------------------------------
// Kernel 5: out[b,o] = relu(sum_d pool[b,d] * W[e_b][o][d]).
// Grid (B, O/32); block 256 = 4 waves; each wave computes 8 outputs,
// holding pool's 1024 floats in wave registers (4 float4/lane).
// ---------------------------------------------------------------------------
__global__ void k_matmul(const float* __restrict__ pool, const float* __restrict__ W,
                         const int* __restrict__ experts, float* __restrict__ out,
                         int B, int D, int O) {
    int b  = blockIdx.x;
    int og = blockIdx.y;
    int tid = threadIdx.x, wv = tid >> 6, ln = tid & 63;
    int o0 = og * 32 + wv * 8;
    int e = experts[b];
    const float4* pool4 = (const float4*)(pool + (size_t)b * D);
    float4 pv[4];
#pragma unroll
    for (int k = 0; k < 4; k++) pv[k] = pool4[k * 64 + ln];
#pragma unroll
    for (int j = 0; j < 8; j++) {
        const float4* Wr = (const float4*)(W + ((size_t)e * O + (o0 + j)) * D);
        float s = 0.f;
#pragma unroll
        for (int k = 0; k < 4; k++) {
            float4 w4 = Wr[k * 64 + ln];
            s += w4.x * pv[k].x + w4.y * pv[k].y + w4.z * pv[k].z + w4.w * pv[k].w;
        }
        for (int off = 32; off; off >>= 1) s += __shfl_down(s, off);
        if (ln == 0) out[(size_t)b * O + o0 + j] = fmaxf(s, 0.f);
    }
}

// ---------------------------------------------------------------------------
extern "C" void kernel_launch(void* const* d_in, const int* in_sizes, int n_in,
                              void* d_out, int out_size, void* d_ws, size_t ws_size,
                              hipStream_t stream) {
    const float* x       = (const float*)d_in[0];
    const int*   experts = (const int*)  d_in[1];
    const float* w1      = (const float*)d_in[2];
    const float* logit   = (const float*)d_in[3];
    const float* w2      = (const float*)d_in[4];
    const float* W       = (const float*)d_in[5];
    float* out = (float*)d_out;

    int B = in_sizes[1];
    int D = in_sizes[2];
    int S = in_sizes[0] / (B * D);
    int O = D;
    int nchunk = S / CH_L;

    float* ws      = (float*)d_ws;
    float* decay   = ws;                       // D floats
    float* coef    = ws + D;                   // D floats
    int*   Kp      = (int*)(ws + 2 * D);       // 1 int (padded to 64 floats)
    float* inv_rms = ws + 2 * D + 64;          // B*S floats
    float* partial = inv_rms + (size_t)B * S;  // B*nchunk*D floats
    float* pool    = partial + (size_t)B * nchunk * D;  // B*D floats

    k_prep<<<1, 256, 0, stream>>>(logit, decay, coef, Kp, D, S);
    k_rms<<<dim3(S / TG, B), 256, 0, stream>>>((const float4*)x, Kp, inv_rms,
                                               B, S, D, nchunk);
    k_ema<<<dim3(nchunk, B), 256, 0, stream>>>((const float4*)x, inv_rms,
                                               (const float4*)decay, (const float4*)coef,
                                               (const float4*)w1, Kp, (float4*)partial,
                                               B, S, D, nchunk);
    k_pool<<<B, 256, 0, stream>>>((const float4*)x, (const float4*)partial,
                                  (const float4*)decay, (const float4*)w2,
                                  Kp, (float4*)pool, B, S, D, nchunk);
    k_matmul<<<dim3(B, O / 32), 256, 0, stream>>>(pool, W, experts, out, B, D, O);
}

// Round 2
// 331.750 us; speedup vs baseline: 1.0489x; 1.0489x over previous
//
#include <hip/hip_runtime.h>
#include <math.h>

#define EPS 1e-6f
#define CH_L 16   // tokens per chunk block (4 waves x 4 tokens, stride-4 interleave)
// Layout assumption (guaranteed by the problem): D = 1024 = 256 float4 = block size.

// ---------------------------------------------------------------------------
// k_prep: decay=sigmoid(logit), cw=(1-decay)*w1, K s.t. max(decay)^K < 1e-12.
// One block of 256 threads, 4 d's per thread.
// ---------------------------------------------------------------------------
__global__ void k_prep(const float4* __restrict__ logit4, const float4* __restrict__ w14,
                       float4* __restrict__ decay4, float4* __restrict__ cw4,
                       int* __restrict__ Kp, int S) {
    int tid = threadIdx.x, wv = tid >> 6, ln = tid & 63;
    float4 lg = logit4[tid];
    float4 w1 = w14[tid];
    float4 dec;
    dec.x = 1.f / (1.f + expf(-lg.x));
    dec.y = 1.f / (1.f + expf(-lg.y));
    dec.z = 1.f / (1.f + expf(-lg.z));
    dec.w = 1.f / (1.f + expf(-lg.w));
    decay4[tid] = dec;
    float4 cw;
    cw.x = (1.f - dec.x) * w1.x;
    cw.y = (1.f - dec.y) * w1.y;
    cw.z = (1.f - dec.z) * w1.z;
    cw.w = (1.f - dec.w) * w1.w;
    cw4[tid] = cw;
    float m = fmaxf(fmaxf(dec.x, dec.y), fmaxf(dec.z, dec.w));
    for (int off = 32; off; off >>= 1) m = fmaxf(m, __shfl_xor(m, off));
    __shared__ float red[4];
    if (ln == 0) red[wv] = m;
    __syncthreads();
    if (tid == 0) {
        float maxd = fmaxf(fmaxf(red[0], red[1]), fmaxf(red[2], red[3]));
        float Kf;
        if (maxd <= 0.f) Kf = 1.f;
        else {
            float lgm = logf(maxd);
            Kf = (lgm >= 0.f) ? (float)S : (logf(1e-12f) / lgm);
        }
        int K = (Kf >= (float)S) ? S : ((int)Kf + 1);
        *Kp = K;
    }
}

// ---------------------------------------------------------------------------
// k_ema: fused rmsnorm + per-chunk EMA partial. Chunk c = tokens
// [S-(c+1)*16, S-c*16). Wave w handles tokens t0+4j+w (j=0..3); each wave
// holds a full token (64 lanes x 16 floats = D), so the sum-of-squares is a
// wave-local butterfly. Exact decomposition: per-token coef = cw*dec^(3-w),
// per-step multiplier dec^4; partial_c = sum over waves; final state =
// sum_c partial_c * dec^(16c). Blocks with c*16 > K early-exit.
// ---------------------------------------------------------------------------
__global__ void k_ema(const float4* __restrict__ x4, const float4* __restrict__ decay4,
                      const float4* __restrict__ cw4, const int* __restrict__ Kp,
                      float4* __restrict__ partial4, int B, int S, int nchunk) {
    int c = blockIdx.x, b = blockIdx.y;
    if (c * CH_L > *Kp) return;
    int tid = threadIdx.x, wv = tid >> 6, ln = tid & 63;

    float4 dec[4], d4p[4], cwp[4];
#pragma unroll
    for (int k = 0; k < 4; k++) {
        float4 d = decay4[k * 64 + ln];
        float4 cw = cw4[k * 64 + ln];
        float4 d2 = make_float4(d.x * d.x, d.y * d.y, d.z * d.z, d.w * d.w);
        d4p[k] = make_float4(d2.x * d2.x, d2.y * d2.y, d2.z * d2.z, d2.w * d2.w);
        // pw = dec^(3-wv)
        float4 pw;
        if (wv == 3)      pw = make_float4(1.f, 1.f, 1.f, 1.f);
        else if (wv == 2) pw = d;
        else if (wv == 1) pw = d2;
        else              pw = make_float4(d2.x * d.x, d2.y * d.y, d2.z * d.z, d2.w * d.w);
        cwp[k] = make_float4(cw.x * pw.x, cw.y * pw.y, cw.z * pw.z, cw.w * pw.w);
        dec[k] = d;
    }

    float4 acc[4];
#pragma unroll
    for (int k = 0; k < 4; k++) acc[k] = make_float4(0.f, 0.f, 0.f, 0.f);

    int t0 = S - (c + 1) * CH_L;
#pragma unroll
    for (int j = 0; j < 4; j++) {
        int t = t0 + 4 * j + wv;
        const float4* xp = x4 + ((size_t)b * S + t) * 256;
        float4 xv[4];
#pragma unroll
        for (int k = 0; k < 4; k++) xv[k] = xp[k * 64 + ln];
        float s = 0.f;
#pragma unroll
        for (int k = 0; k < 4; k++)
            s += xv[k].x * xv[k].x + xv[k].y * xv[k].y + xv[k].z * xv[k].z + xv[k].w * xv[k].w;
        for (int m = 1; m < 64; m <<= 1) s += __shfl_xor(s, m);
        float ir = rsqrtf(s * (1.f / 1024.f) + EPS);
#pragma unroll
        for (int k = 0; k < 4; k++) {
            acc[k].x = acc[k].x * d4p[k].x + xv[k].x * (cwp[k].x * ir);
            acc[k].y = acc[k].y * d4p[k].y + xv[k].y * (cwp[k].y * ir);
            acc[k].z = acc[k].z * d4p[k].z + xv[k].z * (cwp[k].z * ir);
            acc[k].w = acc[k].w * d4p[k].w + xv[k].w * (cwp[k].w * ir);
        }
    }

    __shared__ float4 sm[4][256];
#pragma unroll
    for (int k = 0; k < 4; k++) sm[wv][k * 64 + ln] = acc[k];
    __syncthreads();
    float4 r0 = sm[0][tid], r1 = sm[1][tid], r2 = sm[2][tid], r3 = sm[3][tid];
    float4 r = make_float4(r0.x + r1.x + r2.x + r3.x, r0.y + r1.y + r2.y + r3.y,
                           r0.z + r1.z + r2.z + r3.z, r0.w + r1.w + r2.w + r3.w);
    partial4[((size_t)b * nchunk + c) * 256 + tid] = r;
}

// ---------------------------------------------------------------------------
// k_pool: combine chunk partials (running weight dec^16 per chunk), residual
// add x[:,S-1,:], rmsnorm2 -> pool[b,:]. One block per b.
// ---------------------------------------------------------------------------
__global__ void k_pool(const float4* __restrict__ x4, const float4* __restrict__ partial4,
                       const float4* __restrict__ decay4, const float4* __restrict__ w24,
                       const int* __restrict__ Kp, float4* __restrict__ pool4,
                       int S, int nchunk) {
    int b = blockIdx.x;
    int tid = threadIdx.x, wv = tid >> 6, ln = tid & 63;
    int K = *Kp;
    int cmax = K / CH_L; if (cmax > nchunk - 1) cmax = nchunk - 1;
    float4 d = decay4[tid];
    float4 d2 = make_float4(d.x * d.x, d.y * d.y, d.z * d.z, d.w * d.w);
    float4 d4 = make_float4(d2.x * d2.x, d2.y * d2.y, d2.z * d2.z, d2.w * d2.w);
    float4 d8 = make_float4(d4.x * d4.x, d4.y * d4.y, d4.z * d4.z, d4.w * d4.w);
    float4 dL = make_float4(d8.x * d8.x, d8.y * d8.y, d8.z * d8.z, d8.w * d8.w);
    float4 st = make_float4(0.f, 0.f, 0.f, 0.f);
    float4 wgt = make_float4(1.f, 1.f, 1.f, 1.f);
    for (int c = 0; c <= cmax; c++) {
        float4 p = partial4[((size_t)b * nchunk + c) * 256 + tid];
        st.x += p.x * wgt.x; st.y += p.y * wgt.y;
        st.z += p.z * wgt.z; st.w += p.w * wgt.w;
        wgt.x *= dL.x; wgt.y *= dL.y; wgt.z *= dL.z; wgt.w *= dL.w;
    }
    float4 xl = x4[((size_t)b * S + (S - 1)) * 256 + tid];
    float4 y = make_float4(xl.x + st.x, xl.y + st.y, xl.z + st.z, xl.w + st.w);
    float ss = y.x * y.x + y.y * y.y + y.z * y.z + y.w * y.w;
    for (int m = 1; m < 64; m <<= 1) ss += __shfl_xor(ss, m);
    __shared__ float red[4];
    __shared__ float tot;
    if (ln == 0) red[wv] = ss;
    __syncthreads();
    if (tid == 0) tot = red[0] + red[1] + red[2] + red[3];
    __syncthreads();
    float ir = rsqrtf(tot * (1.f / 1024.f) + EPS);
    float4 w2 = w24[tid];
    pool4[(size_t)b * 256 + tid] = make_float4(y.x * ir * w2.x, y.y * ir * w2.y,
                                               y.z * ir * w2.z, y.w * ir * w2.w);
}

// ---------------------------------------------------------------------------
// k_matmul: out[b,o] = relu(dot(pool[b,:], W[e_b][o][:])). Grid (B, O/32);
// 4 waves/block, 8 outputs/wave, pool held in wave registers.
// ---------------------------------------------------------------------------
__global__ void k_matmul(const float* __restrict__ pool, const float* __restrict__ W,
                         const int* __restrict__ experts, float* __restrict__ out,
                         int D, int O) {
    int b  = blockIdx.x;
    int og = blockIdx.y;
    int tid = threadIdx.x, wv = tid >> 6, ln = tid & 63;
    int o0 = og * 32 + wv * 8;
    int e = experts[b];
    const float4* pool4 = (const float4*)(pool + (size_t)b * D);
    float4 pv[4];
#pragma unroll
    for (int k = 0; k < 4; k++) pv[k] = pool4[k * 64 + ln];
#pragma unroll
    for (int j = 0; j < 8; j++) {
        const float4* Wr = (const float4*)(W + ((size_t)e * O + (o0 + j)) * D);
        float s = 0.f;
#pragma unroll
        for (int k = 0; k < 4; k++) {
            float4 w4 = Wr[k * 64 + ln];
            s += w4.x * pv[k].x + w4.y * pv[k].y + w4.z * pv[k].z + w4.w * pv[k].w;
        }
        for (int off = 32; off; off >>= 1) s += __shfl_down(s, off);
        if (ln == 0) out[(size_t)b * O + o0 + j] = fmaxf(s, 0.f);
    }
}

// ---------------------------------------------------------------------------
extern "C" void kernel_launch(void* const* d_in, const int* in_sizes, int n_in,
                              void* d_out, int out_size, void* d_ws, size_t ws_size,
                              hipStream_t stream) {
    const float* x       = (const float*)d_in[0];
    const int*   experts = (const int*)  d_in[1];
    const float* w1      = (const float*)d_in[2];
    const float* logit   = (const float*)d_in[3];
    const float* w2      = (const float*)d_in[4];
    const float* W       = (const float*)d_in[5];
    float* out = (float*)d_out;

    int B = in_sizes[1];
    int D = in_sizes[2];           // = 1024
    int S = in_sizes[0] / (B * D); // = 4096
    int O = D;
    int nchunk = S / CH_L;         // = 256

    float* ws      = (float*)d_ws;
    float* decay   = ws;                        // D floats
    float* cw      = ws + D;                    // D floats
    int*   Kp      = (int*)(ws + 2 * D);        // 1 int (64-float pad)
    float* partial = ws + 2 * D + 64;           // B*nchunk*D floats (~16 MB)
    float* pool    = partial + (size_t)B * nchunk * D;  // B*D floats

    k_prep<<<1, 256, 0, stream>>>((const float4*)logit, (const float4*)w1,
                                  (float4*)decay, (float4*)cw, Kp, S);
    k_ema<<<dim3(nchunk, B), 256, 0, stream>>>((const float4*)x, (const float4*)decay,
                                               (const float4*)cw, Kp,
                                               (float4*)partial, B, S, nchunk);
    k_pool<<<B, 256, 0, stream>>>((const float4*)x, (const float4*)partial,
                                  (const float4*)decay, (const float4*)w2,
                                  Kp, (float4*)pool, S, nchunk);
    k_matmul<<<dim3(B, O / 32), 256, 0, stream>>>(pool, W, experts, out, D, O);
}